// Round 8
// baseline (1072.955 us; speedup 1.0000x reference)
//
#include <hip/hip_runtime.h>

typedef __attribute__((ext_vector_type(8))) short short8;
typedef __attribute__((ext_vector_type(4))) float float4v;
typedef __attribute__((ext_vector_type(4))) int int4v;
typedef __attribute__((ext_vector_type(4))) unsigned short ushort4v;

#define NBOX 13392   // 108*124 bev cells (n = d*124 + wj)
#define ZC 9
#define KOFT 2304    // 9*256, k = z*256+c
#define NPIX 3348    // 62*54
#define NBLK0 105    // ceil(13392/128)
#define NBLKC 27     // ceil(3348/128)
#define TILEK 4096   // shorts per 8KB step-tile [kc4][row128][8]
#define NBSTRIDE 294912  // 72 steps * 4096 shorts per row-block / col-block
#define OFT_SPLIT 4      // 18 steps per split chunk

__device__ __forceinline__ unsigned short f2bf(float f) {
  union { float f; unsigned int i; } v; v.f = f;
  unsigned int r = v.i + 0x7FFFu + ((v.i >> 16) & 1u);
  return (unsigned short)(r >> 16);
}
__device__ __forceinline__ float bf2f(unsigned short u) {
  union { unsigned int i; float f; } v; v.i = ((unsigned int)u) << 16; return v.f;
}

// async 16B global->LDS (wave-uniform LDS base + lane*16)
__device__ __forceinline__ void async16(const unsigned short* g, unsigned short* l) {
  __builtin_amdgcn_global_load_lds(
      (const __attribute__((address_space(1))) unsigned int*)g,
      (__attribute__((address_space(3))) unsigned int*)l, 16, 0, 0);
}

// ---------------- alpha/beta epilogue constants + zero MEANS + zero page ---
__global__ void k_alpha_beta(const float* __restrict__ oft_b,
                             const float* __restrict__ g1, const float* __restrict__ b1,
                             const float* __restrict__ m1, const float* __restrict__ v1,
                             const float* __restrict__ g2, const float* __restrict__ b2,
                             const float* __restrict__ m2, const float* __restrict__ v2,
                             float* __restrict__ ALPHA, float* __restrict__ BETA,
                             float* __restrict__ MEANS, unsigned short* __restrict__ ZPAGE) {
  int g = blockIdx.x, c = threadIdx.x;
  float al, be;
  if (g < 5) { al = 1.f; be = oft_b[g * 256 + c]; MEANS[g * 256 + c] = 0.f; }
  else {
    const float* gg = (g == 5) ? g1 : g2;
    const float* bb = (g == 5) ? b1 : b2;
    const float* mm = (g == 5) ? m1 : m2;
    const float* vv = (g == 5) ? v1 : v2;
    al = gg[c] / sqrtf(vv[c] + 1e-5f);
    be = bb[c] - mm[c] * al;
  }
  ALPHA[g * 256 + c] = al; BETA[g * 256 + c] = be;
  if (g == 0) ZPAGE[c] = 0;
}

// ---------------- oft weights -> tiled B: [sc][cb2][s72][kc4][row128][j8] ---
__global__ void k_wpermT(const float* __restrict__ w, unsigned short* __restrict__ wp) {
  int idx = blockIdx.x * 256 + threadIdx.x;  // < 5*589824
  int sc = idx / 589824;
  int r  = idx % 589824;
  int j   = r & 7;
  int row = (r >> 3) & 127;
  int kc  = (r >> 10) & 3;
  int cs  = r >> 12;            // cb*72 + s
  int cb  = cs / 72, s = cs % 72;
  int oc = cb * 128 + row;
  int k  = s * 32 + kc * 8 + j; // k' = z*256 + c
  int z = k >> 8, c = k & 255;
  wp[idx] = f2bf(w[((size_t)sc * 256 + oc) * 2304 + c * 9 + z]);
}

// ---------------- conv1 weights -> tiled [cb2][r9][s40][kc4][row128][j8], *satt
__global__ void k_wperm1T(const float* __restrict__ w, const float* __restrict__ satt,
                          unsigned short* __restrict__ wp) {
  int idx = blockIdx.x * 256 + threadIdx.x;  // < 2*9*40*4096 = 2949120
  int j   = idx & 7;
  int row = (idx >> 3) & 127;
  int kc  = (idx >> 10) & 3;
  int rest = idx >> 12;          // (cb*9 + r)*40 + s
  int s = rest % 40; rest /= 40;
  int r = rest % 9;  int cb = rest / 9;
  int oc = cb * 128 + row;
  int ic = s * 32 + kc * 8 + j;  // < 1280
  wp[idx] = f2bf(w[(size_t)oc * 11520 + ic * 9 + r] * satt[ic]);
}

// ---------------- conv2 weights -> tiled [cb2][r9][s8][kc4][row128][j8] ----
__global__ void k_wperm2T(const float* __restrict__ w, unsigned short* __restrict__ wp) {
  int idx = blockIdx.x * 256 + threadIdx.x;  // < 2*9*8*4096 = 589824
  int j   = idx & 7;
  int row = (idx >> 3) & 127;
  int kc  = (idx >> 10) & 3;
  int rest = idx >> 12;          // (cb*9 + r)*8 + s
  int s = rest % 8; rest /= 8;
  int r = rest % 9; int cb = rest / 9;
  int oc = cb * 128 + row;
  int ic = s * 32 + kc * 8 + j;  // < 256
  wp[idx] = f2bf(w[(size_t)oc * 2304 + ic * 9 + r]);
}

// ---------------- tap table: per (z,n) box, 16 (byte-offset, weight) pairs -
// layout per box (128 B): int off[16]; float w[16].  weight folds
// sign * bilinear * 1/area; OOB taps -> (0, 0.0f).
__global__ void k_taps(const float* __restrict__ calib, int* __restrict__ taps,
                       int Hf, int Wf, float areaScale) {
  int idx = blockIdx.x * 256 + threadIdx.x;
  if (idx >= ZC * NBOX) return;
  int z = idx / NBOX, n = idx % NBOX;
  int d = n / 124, wj = n % 124;
  float P[12];
#pragma unroll
  for (int i = 0; i < 12; ++i) P[i] = calib[i];
  auto proj = [&](int k, int i, int j, float& nx, float& ny) {
    float X = 0.64f * (float)i;
    float Y = 39.68f - 0.64f * (float)j;
    float Z = 2.76f - 0.64f * (float)k;
    float hx = P[0] * X + P[1] * Y + P[2]  * Z + P[3];
    float hy = P[4] * X + P[5] * Y + P[6]  * Z + P[7];
    float hz = P[8] * X + P[9] * Y + P[10] * Z + P[11];
    float px = hx / hz, py = hy / hz;
    nx = 2.f * px / 1280.f - 1.f; nx = fminf(fmaxf(nx, -1.f), 1.f);
    ny = 2.f * py / 384.f  - 1.f; ny = fminf(fmaxf(ny, -1.f), 1.f);
  };
  float ax, ay, bx, by, cx, cy, dx, dy;
  proj(z,     d,     wj,     ax, ay);
  proj(z,     d + 1, wj,     bx, by);
  proj(z + 1, d + 1, wj + 1, cx, cy);
  proj(z + 1, d,     wj + 1, dx, dy);
  float x0 = fminf(ax, bx), y0 = fminf(ay, by);
  float x1 = fmaxf(cx, dx), y1 = fmaxf(cy, dy);
  float rawA = (x1 - x0) * (y1 - y0) * areaScale;
  float inv = (rawA > 0.f) ? (1.f / (rawA + 1e-6f)) : 0.f;
  int   off[16];
  float w[16];
#pragma unroll
  for (int pt = 0; pt < 4; ++pt) {
    float gx = (pt == 0 || pt == 3) ? x0 : x1;
    float gy = (pt == 0 || pt == 2) ? y0 : y1;
    float sign = (pt < 2) ? 1.f : -1.f;
    float u = (gx + 1.f) * ((float)Wf * 0.5f) - 0.5f;
    float v = (gy + 1.f) * ((float)Hf * 0.5f) - 0.5f;
    float uf = floorf(u), vf = floorf(v);
    float wx = u - uf, wy = v - vf;
    int xi = (int)uf, yi = (int)vf;
#pragma unroll
    for (int t = 0; t < 4; ++t) {
      int xx = xi + (t & 1), yy = yi + (t >> 1);
      bool ok = ((unsigned)xx < (unsigned)Wf) && ((unsigned)yy < (unsigned)Hf);
      float wt = ((t & 1) ? wx : 1.f - wx) * ((t >> 1) ? wy : 1.f - wy);
      off[pt * 4 + t] = ok ? (yy * Wf + xx) * 1024 : 0;   // byte offset, 256ch*4B
      w[pt * 4 + t]   = ok ? sign * wt * inv : 0.f;
    }
  }
  int4v* ob = (int4v*)(taps + (size_t)idx * 32);
#pragma unroll
  for (int i = 0; i < 4; ++i)
    ob[i] = (int4v){off[4 * i], off[4 * i + 1], off[4 * i + 2], off[4 * i + 3]};
  float4v* wb = (float4v*)ob;
#pragma unroll
  for (int i = 0; i < 4; ++i)
    wb[4 + i] = (float4v){w[4 * i], w[4 * i + 1], w[4 * i + 2], w[4 * i + 3]};
}

// ---------------- merged feats transpose: [256][S] f32 -> II [S][256] ------
__global__ void k_transpose_all(const float* __restrict__ f0, const float* __restrict__ f1,
                                const float* __restrict__ f2, const float* __restrict__ f3,
                                const float* __restrict__ f4, float* __restrict__ II) {
  int b = blockIdx.x;
  int sc, cx;
  if (b < 480)      { sc = 0; cx = b; }
  else if (b < 600) { sc = 1; cx = b - 480; }
  else if (b < 630) { sc = 2; cx = b - 600; }
  else if (b < 638) { sc = 3; cx = b - 630; }
  else              { sc = 4; cx = b - 638; }
  const int Ss[5] = {30720, 7680, 1920, 480, 120};
  const size_t IIof[5] = {0, 7864320, 9830400, 10321920, 10444800};
  const float* srcs[5] = {f0, f1, f2, f3, f4};
  int S = Ss[sc];
  const float* src = srcs[sc];
  float* dst = II + IIof[sc];
  __shared__ float tile[64][65];
  int t = threadIdx.x;
  int wave = t >> 6, lane = t & 63;
  int s0 = cx * 64, c0 = blockIdx.y * 64;
#pragma unroll
  for (int i = 0; i < 16; ++i) {
    int c_l = wave * 16 + i;
    if (s0 + lane < S) tile[c_l][lane] = src[(size_t)(c0 + c_l) * S + s0 + lane];
  }
  __syncthreads();
#pragma unroll
  for (int i = 0; i < 16; ++i) {
    int s_l = wave * 16 + i;
    if (s0 + s_l < S) dst[(size_t)(s0 + s_l) * 256 + c0 + lane] = tile[lane][s_l];
  }
}

// ---------------- merged cumsum over w: grid 186 ---------------------------
__global__ void k_cumw_all(float* __restrict__ II) {
  int b = blockIdx.x;
  int sc, h;
  if (b < 96)       { sc = 0; h = b; }
  else if (b < 144) { sc = 1; h = b - 96; }
  else if (b < 168) { sc = 2; h = b - 144; }
  else if (b < 180) { sc = 3; h = b - 168; }
  else              { sc = 4; h = b - 180; }
  const int Wfs[5] = {320, 160, 80, 40, 20};
  const size_t IIof[5] = {0, 7864320, 9830400, 10321920, 10444800};
  int Wf = Wfs[sc];
  float* p = II + IIof[sc] + (size_t)h * Wf * 256 + threadIdx.x;
  float acc = 0.f;
#pragma unroll 4
  for (int w = 0; w < Wf; ++w) { acc += p[(size_t)w * 256]; p[(size_t)w * 256] = acc; }
}

// ---------------- merged cumsum over h: grid 620 ---------------------------
__global__ void k_cumh_all(float* __restrict__ II) {
  int b = blockIdx.x;
  int sc, w;
  if (b < 320)      { sc = 0; w = b; }
  else if (b < 480) { sc = 1; w = b - 320; }
  else if (b < 560) { sc = 2; w = b - 480; }
  else if (b < 600) { sc = 3; w = b - 560; }
  else              { sc = 4; w = b - 600; }
  const int Wfs[5] = {320, 160, 80, 40, 20};
  const int Hfs[5] = {96, 48, 24, 12, 6};
  const size_t IIof[5] = {0, 7864320, 9830400, 10321920, 10444800};
  int Hf = Hfs[sc];
  size_t stride = (size_t)Wfs[sc] * 256;
  float* p = II + IIof[sc] + (size_t)w * 256 + threadIdx.x;
  float acc = 0.f;
#pragma unroll 4
  for (int h = 0; h < Hf; ++h) { acc += p[h * stride]; p[h * stride] = acc; }
}

// ---------------- box sampler: wave = one n, 3 z per wave, table-driven ----
__global__ void k_sample(const float* __restrict__ ii, const int* __restrict__ taps,
                         unsigned short* __restrict__ voxT) {
  int wave = threadIdx.x >> 6, lane = threadIdx.x & 63;
  int n = blockIdx.x * 4 + wave;
  int zg = blockIdx.y * 3;
  const char* iib = (const char*)ii + (lane << 4);   // + c4*4 bytes
  int nb = n >> 7, row = n & 127;
  unsigned short* vb = voxT + (size_t)nb * NBSTRIDE + (size_t)row * 8
                     + (lane >> 3) * 4096 + ((lane >> 1) & 3) * 1024 + (lane & 1) * 4;
#pragma unroll
  for (int dz = 0; dz < 3; ++dz) {
    int z = zg + dz;
    const int4v* tb = (const int4v*)(taps + (size_t)(z * NBOX + n) * 32);
    int4v o0 = tb[0], o1 = tb[1], o2 = tb[2], o3 = tb[3];
    const float4v* tw = (const float4v*)tb;
    float4v w0 = tw[4], w1 = tw[5], w2 = tw[6], w3 = tw[7];
    float4v a0 = {0.f, 0.f, 0.f, 0.f}, a1 = a0;
#define TAP(o, w, acc) { float4v t_ = *(const float4v*)(iib + (size_t)(unsigned)(o)); acc += t_ * (w); }
    TAP(o0.x, w0.x, a0) TAP(o0.y, w0.y, a1) TAP(o0.z, w0.z, a0) TAP(o0.w, w0.w, a1)
    TAP(o1.x, w1.x, a0) TAP(o1.y, w1.y, a1) TAP(o1.z, w1.z, a0) TAP(o1.w, w1.w, a1)
    TAP(o2.x, w2.x, a0) TAP(o2.y, w2.y, a1) TAP(o2.z, w2.z, a0) TAP(o2.w, w2.w, a1)
    TAP(o3.x, w3.x, a0) TAP(o3.y, w3.y, a1) TAP(o3.z, w3.z, a0) TAP(o3.w, w3.w, a1)
#undef TAP
    float4v acc = a0 + a1;
    ushort4v o;
#pragma unroll
    for (int j = 0; j < 4; ++j) o[j] = f2bf(acc[j]);
    *(ushort4v*)(vb + z * 32768) = o;
  }
}

// ---------------- OFT GEMM, split-K=4: raw f32 partials --------------------
__global__ __launch_bounds__(256) void k_gemmT(
    const unsigned short* __restrict__ AT, const unsigned short* __restrict__ BT,
    float* __restrict__ part) {
  __shared__ unsigned short lsA[4096];
  __shared__ unsigned short lsB[4096];
  int t = threadIdx.x;
  int lane = t & 63, wave = t >> 6;
  int l15 = lane & 15, quad = lane >> 4;
  int nb = blockIdx.x, cb = blockIdx.y, ks = blockIdx.z;
  int wrow = (wave >> 1) * 64, wcol = (wave & 1) * 64;

  const unsigned short* ga = AT + (size_t)nb * NBSTRIDE + (size_t)ks * 18 * TILEK + t * 8;
  const unsigned short* gb = BT + (size_t)cb * NBSTRIDE + (size_t)ks * 18 * TILEK + t * 8;
  unsigned short* ldA = lsA + t * 8;
  unsigned short* ldB = lsB + t * 8;

  float4v acc[4][4];
#pragma unroll
  for (int mi = 0; mi < 4; ++mi)
#pragma unroll
    for (int ni = 0; ni < 4; ++ni) acc[mi][ni] = (float4v){0.f, 0.f, 0.f, 0.f};

  for (int s = 0; s < 18; ++s) {
    async16(ga, ldA);
    async16(ga + 2048, ldA + 2048);
    async16(gb, ldB);
    async16(gb + 2048, ldB + 2048);
    ga += TILEK; gb += TILEK;
    __syncthreads();
    short8 af[4], bf[4];
    const short8* pA = (const short8*)lsA;
    const short8* pB = (const short8*)lsB;
#pragma unroll
    for (int mi = 0; mi < 4; ++mi) af[mi] = pA[quad * 128 + wrow + mi * 16 + l15];
#pragma unroll
    for (int ni = 0; ni < 4; ++ni) bf[ni] = pB[quad * 128 + wcol + ni * 16 + l15];
#pragma unroll
    for (int mi = 0; mi < 4; ++mi)
#pragma unroll
      for (int ni = 0; ni < 4; ++ni)
        acc[mi][ni] = __builtin_amdgcn_mfma_f32_16x16x32_bf16(af[mi], bf[ni], acc[mi][ni], 0, 0, 0);
    __syncthreads();
  }

#pragma unroll
  for (int mi = 0; mi < 4; ++mi) {
    int nb0 = nb * 128 + wrow + mi * 16 + quad * 4;
#pragma unroll
    for (int j = 0; j < 4; ++j) {
      int nn = nb0 + j;
      if (nn < NBOX) {
#pragma unroll
        for (int ni = 0; ni < 4; ++ni) {
          int oc = cb * 128 + wcol + ni * 16 + l15;
          part[((size_t)ks * NBOX + nn) * 256 + oc] = acc[mi][ni][j];
        }
      }
    }
  }
}

// reduce OFT partials -> XBUF [n][1280] @ choff (bias + relu, alpha=1)
__global__ void k_redoft(const float* __restrict__ part, const float* __restrict__ beta,
                         unsigned short* __restrict__ xbuf, int choff) {
  int n = blockIdx.x, oc = threadIdx.x;
  float v = part[(size_t)n * 256 + oc]
          + part[((size_t)NBOX + n) * 256 + oc]
          + part[((size_t)2 * NBOX + n) * 256 + oc]
          + part[((size_t)3 * NBOX + n) * 256 + oc];
  v += beta[oc];
  v = v > 0.f ? v : 0.f;
  xbuf[(size_t)n * 1280 + choff + oc] = f2bf(v);
}

// ---------------- conv GEMM, split by tap r: raw f32 partials --------------
template <int MODE>
__global__ __launch_bounds__(256) void k_gemmS(
    const unsigned short* __restrict__ A, const unsigned short* __restrict__ BT,
    float* __restrict__ part, const unsigned short* __restrict__ zpage) {
  constexpr int KIC   = (MODE == 1) ? 1280 : 256;
  constexpr int STEPS = KIC / 32;
  __shared__ unsigned short lsA[4096];
  __shared__ unsigned short lsB[4096];
  int t = threadIdx.x;
  int lane = t & 63, wave = t >> 6;
  int l15 = lane & 15, quad = lane >> 4;
  int n0 = blockIdx.x * 128, oc0 = blockIdx.y * 128;
  int r = blockIdx.z;
  int wrow = (wave >> 1) * 64, wcol = (wave & 1) * 64;
  int srow = t & 127, skc = t >> 7;

  int p = n0 + srow;
  int oy = p / 54, ox = p - oy * 54;
  int ky = r / 3, kx = r - ky * 3;
  bool valid; int sp;
  if (MODE == 1) {
    int ih = 2 * oy + ky - 1, iw = 2 * ox + kx - 1;
    valid = (p < NPIX) && ((unsigned)ih < 124u) && ((unsigned)iw < 108u);
    sp = iw * 124 + ih;
  } else {
    int ih = oy + ky - 1, iw = ox + kx - 1;
    valid = (p < NPIX) && ((unsigned)ih < 62u) && ((unsigned)iw < 54u);
    sp = ih * 54 + iw;
  }
  const unsigned short* ga = valid ? (A + (size_t)sp * KIC + skc * 8) : zpage;
  int astep = valid ? 32 : 0;
  const unsigned short* gb = BT + ((size_t)(blockIdx.y * 9 + r) * STEPS) * TILEK + t * 8;
  unsigned short* ldA = lsA + t * 8;
  unsigned short* ldB = lsB + t * 8;

  float4v acc[4][4];
#pragma unroll
  for (int mi = 0; mi < 4; ++mi)
#pragma unroll
    for (int ni = 0; ni < 4; ++ni) acc[mi][ni] = (float4v){0.f, 0.f, 0.f, 0.f};

  for (int s = 0; s < STEPS; ++s) {
    async16(ga, ldA);
    async16(ga + 16, ldA + 2048);
    async16(gb, ldB);
    async16(gb + 2048, ldB + 2048);
    ga += astep; gb += TILEK;
    __syncthreads();
    short8 af[4], bf[4];
    const short8* pA = (const short8*)lsA;
    const short8* pB = (const short8*)lsB;
#pragma unroll
    for (int mi = 0; mi < 4; ++mi) af[mi] = pA[quad * 128 + wrow + mi * 16 + l15];
#pragma unroll
    for (int ni = 0; ni < 4; ++ni) bf[ni] = pB[quad * 128 + wcol + ni * 16 + l15];
#pragma unroll
    for (int mi = 0; mi < 4; ++mi)
#pragma unroll
      for (int ni = 0; ni < 4; ++ni)
        acc[mi][ni] = __builtin_amdgcn_mfma_f32_16x16x32_bf16(af[mi], bf[ni], acc[mi][ni], 0, 0, 0);
    __syncthreads();
  }

#pragma unroll
  for (int mi = 0; mi < 4; ++mi) {
    int nb0 = n0 + wrow + mi * 16 + quad * 4;
#pragma unroll
    for (int j = 0; j < 4; ++j) {
      int nn = nb0 + j;
      if (nn < NPIX) {
#pragma unroll
        for (int ni = 0; ni < 4; ++ni) {
          int oc = oc0 + wcol + ni * 16 + l15;
          part[((size_t)r * NPIX + nn) * 256 + oc] = acc[mi][ni][j];
        }
      }
    }
  }
}

// reduce conv partials (9 taps) with alpha/beta + relu
template <bool F32OUT>
__global__ void k_redconv(const float* __restrict__ part, const float* __restrict__ alpha,
                          const float* __restrict__ beta, void* __restrict__ outv) {
  int p = blockIdx.x, oc = threadIdx.x;
  float v = 0.f;
#pragma unroll
  for (int r = 0; r < 9; ++r) v += part[((size_t)r * NPIX + p) * 256 + oc];
  v = v * alpha[oc] + beta[oc];
  v = v > 0.f ? v : 0.f;
  if (F32OUT) ((float*)outv)[(size_t)oc * NPIX + p] = v;
  else ((unsigned short*)outv)[(size_t)p * 256 + oc] = f2bf(v);
}

// ---------------- channel means over XBUF [n][1280] ------------------------
__global__ void k_means2(const unsigned short* __restrict__ x, float* __restrict__ means) {
  int tid = threadIdx.x;
  int r0 = blockIdx.x * 64;
  float part[5] = {0.f, 0.f, 0.f, 0.f, 0.f};
  for (int i = 0; i < 64; ++i) {
    int row = r0 + i;
    if (row < NBOX) {
      const unsigned short* rp = x + (size_t)row * 1280;
#pragma unroll
      for (int g = 0; g < 5; ++g) part[g] += bf2f(rp[g * 256 + tid]);
    }
  }
#pragma unroll
  for (int g = 0; g < 5; ++g) atomicAdd(&means[g * 256 + tid], part[g]);
}

__global__ void k_att(const float* __restrict__ means, const float* __restrict__ aw,
                      const float* __restrict__ ab, float* __restrict__ satt) {
  int sc = blockIdx.x, c = threadIdx.x;
  __shared__ float m[256];
  m[c] = means[sc * 256 + c] * (1.f / (float)NBOX);
  __syncthreads();
  float acc = ab[c];
  for (int j = 0; j < 256; ++j) acc += m[j] * aw[c * 256 + j];
  satt[sc * 256 + c] = 1.f / (1.f + expf(-acc));
}

extern "C" void kernel_launch(void* const* d_in, const int* in_sizes, int n_in,
                              void* d_out, int out_size, void* d_ws, size_t ws_size,
                              hipStream_t stream) {
  const float* feats[5];
  for (int i = 0; i < 5; ++i) feats[i] = (const float*)d_in[i];
  const float* calib   = (const float*)d_in[5];
  const float* oft_w   = (const float*)d_in[6];
  const float* oft_b   = (const float*)d_in[7];
  const float* att_w   = (const float*)d_in[8];
  const float* att_b   = (const float*)d_in[9];
  const float* conv1_w = (const float*)d_in[10];
  const float* bn1g = (const float*)d_in[11];
  const float* bn1b = (const float*)d_in[12];
  const float* bn1m = (const float*)d_in[13];
  const float* bn1v = (const float*)d_in[14];
  const float* conv2_w = (const float*)d_in[15];
  const float* bn2g = (const float*)d_in[16];
  const float* bn2b = (const float*)d_in[17];
  const float* bn2m = (const float*)d_in[18];
  const float* bn2v = (const float*)d_in[19];

  char* ws = (char*)d_ws;
  size_t off = 0;
  auto alloc = [&](size_t bytes) -> void* {
    void* p = ws + off; off += (bytes + 255) & ~(size_t)255; return p;
  };
  unsigned short* WPERMT = (unsigned short*)alloc((size_t)5 * 589824 * 2);
  unsigned short* WC1T   = (unsigned short*)alloc((size_t)2949120 * 2);
  unsigned short* WC2T   = (unsigned short*)alloc((size_t)589824 * 2);
  float*          II     = (float*)alloc((size_t)10475520 * 4);
  unsigned short* VOXT   = (unsigned short*)alloc((size_t)NBLK0 * NBSTRIDE * 2);
  unsigned short* XBUF   = (unsigned short*)alloc((size_t)NBOX * 1280 * 2);
  unsigned short* Y1     = (unsigned short*)alloc((size_t)NPIX * 256 * 2);
  float*          PART   = (float*)alloc((size_t)OFT_SPLIT * NBOX * 256 * 4); // 54.8 MB
  float*          MEANS  = (float*)alloc(1280 * 4);
  float*          SATT   = (float*)alloc(1280 * 4);
  float*          ALPHA  = (float*)alloc(7 * 256 * 4);
  float*          BETA   = (float*)alloc(7 * 256 * 4);
  unsigned short* ZPAGE  = (unsigned short*)alloc(256 * 2);
  // TAPS aliases PART: taps for scale s are consumed by k_sample(s) BEFORE
  // k_gemmT(s) writes PART; k_taps(s+1) runs after k_redoft(s) read PART.
  int* TAPS = (int*)PART;   // 9*13392*128 B = 15.4 MB <= 54.8 MB
  (void)ws_size; (void)in_sizes; (void)n_in; (void)out_size;

  static const int HFs[5] = {96, 48, 24, 12, 6};
  static const int WFs[5] = {320, 160, 80, 40, 20};
  static const size_t IIoff[5] = {0, 7864320, 9830400, 10321920, 10444800};

  k_alpha_beta<<<7, 256, 0, stream>>>(oft_b, bn1g, bn1b, bn1m, bn1v,
                                      bn2g, bn2b, bn2m, bn2v, ALPHA, BETA, MEANS, ZPAGE);
  k_wpermT<<<11520, 256, 0, stream>>>(oft_w, WPERMT);
  k_wperm2T<<<2304, 256, 0, stream>>>(conv2_w, WC2T);

  k_transpose_all<<<dim3(640, 4), 256, 0, stream>>>(feats[0], feats[1], feats[2],
                                                    feats[3], feats[4], II);
  k_cumw_all<<<186, 256, 0, stream>>>(II);
  k_cumh_all<<<620, 256, 0, stream>>>(II);

  for (int s = 0; s < 5; ++s) {
    k_taps<<<(ZC * NBOX + 255) / 256, 256, 0, stream>>>(
        calib, TAPS, HFs[s], WFs[s], (float)(HFs[s] * WFs[s]) * 0.25f);
    k_sample<<<dim3(NBOX / 4, 3), 256, 0, stream>>>(II + IIoff[s], TAPS, VOXT);
    k_gemmT<<<dim3(NBLK0, 2, OFT_SPLIT), 256, 0, stream>>>(
        VOXT, WPERMT + (size_t)s * 589824, PART);
    k_redoft<<<NBOX, 256, 0, stream>>>(PART, BETA + s * 256, XBUF, s * 256);
  }
  k_means2<<<(NBOX + 63) / 64, 256, 0, stream>>>(XBUF, MEANS);
  k_att<<<5, 256, 0, stream>>>(MEANS, att_w, att_b, SATT);
  k_wperm1T<<<11520, 256, 0, stream>>>(conv1_w, SATT, WC1T);

  k_gemmS<1><<<dim3(NBLKC, 2, 9), 256, 0, stream>>>(XBUF, WC1T, PART, ZPAGE);
  k_redconv<false><<<NPIX, 256, 0, stream>>>(PART, ALPHA + 5 * 256, BETA + 5 * 256, Y1);

  k_gemmS<2><<<dim3(NBLKC, 2, 9), 256, 0, stream>>>(Y1, WC2T, PART, ZPAGE);
  k_redconv<true><<<NPIX, 256, 0, stream>>>(PART, ALPHA + 6 * 256, BETA + 6 * 256, d_out);
}

// Round 9
// 1070.844 us; speedup vs baseline: 1.0020x; 1.0020x over previous
//
#include <hip/hip_runtime.h>

typedef __attribute__((ext_vector_type(8))) short short8;
typedef __attribute__((ext_vector_type(4))) float float4v;
typedef __attribute__((ext_vector_type(4))) int int4v;
typedef __attribute__((ext_vector_type(4))) unsigned short ushort4v;

#define NBOX 13392   // 108*124 bev cells (n = d*124 + wj)
#define ZC 9
#define KOFT 2304    // 9*256, k = z*256+c
#define NPIX 3348    // 62*54
#define NBLK0 105    // ceil(13392/128)
#define NBLKC 27     // ceil(3348/128)
#define TILEK 4096   // shorts per 8KB step-tile [kc4][row128][8]
#define NBSTRIDE 294912  // 72 steps * 4096 shorts per row-block / col-block
#define OFT_SPLIT 4      // 18 steps per split chunk

__device__ __forceinline__ unsigned short f2bf(float f) {
  union { float f; unsigned int i; } v; v.f = f;
  unsigned int r = v.i + 0x7FFFu + ((v.i >> 16) & 1u);
  return (unsigned short)(r >> 16);
}
__device__ __forceinline__ float bf2f(unsigned short u) {
  union { unsigned int i; float f; } v; v.i = ((unsigned int)u) << 16; return v.f;
}

// async 16B global->LDS (wave-uniform LDS base + lane*16)
__device__ __forceinline__ void async16(const unsigned short* g, unsigned short* l) {
  __builtin_amdgcn_global_load_lds(
      (const __attribute__((address_space(1))) unsigned int*)g,
      (__attribute__((address_space(3))) unsigned int*)l, 16, 0, 0);
}

// ---------------- alpha/beta epilogue constants + zero MEANS + zero page ---
__global__ void k_alpha_beta(const float* __restrict__ oft_b,
                             const float* __restrict__ g1, const float* __restrict__ b1,
                             const float* __restrict__ m1, const float* __restrict__ v1,
                             const float* __restrict__ g2, const float* __restrict__ b2,
                             const float* __restrict__ m2, const float* __restrict__ v2,
                             float* __restrict__ ALPHA, float* __restrict__ BETA,
                             float* __restrict__ MEANS, unsigned short* __restrict__ ZPAGE) {
  int g = blockIdx.x, c = threadIdx.x;
  float al, be;
  if (g < 5) { al = 1.f; be = oft_b[g * 256 + c]; MEANS[g * 256 + c] = 0.f; }
  else {
    const float* gg = (g == 5) ? g1 : g2;
    const float* bb = (g == 5) ? b1 : b2;
    const float* mm = (g == 5) ? m1 : m2;
    const float* vv = (g == 5) ? v1 : v2;
    al = gg[c] / sqrtf(vv[c] + 1e-5f);
    be = bb[c] - mm[c] * al;
  }
  ALPHA[g * 256 + c] = al; BETA[g * 256 + c] = be;
  if (g == 0) ZPAGE[c] = 0;
}

// ---------------- oft weights -> tiled B: [sc][cb2][s72][kc4][row128][j8] ---
__global__ void k_wpermT(const float* __restrict__ w, unsigned short* __restrict__ wp) {
  int idx = blockIdx.x * 256 + threadIdx.x;  // < 5*589824
  int sc = idx / 589824;
  int r  = idx % 589824;
  int j   = r & 7;
  int row = (r >> 3) & 127;
  int kc  = (r >> 10) & 3;
  int cs  = r >> 12;            // cb*72 + s
  int cb  = cs / 72, s = cs % 72;
  int oc = cb * 128 + row;
  int k  = s * 32 + kc * 8 + j; // k' = z*256 + c
  int z = k >> 8, c = k & 255;
  wp[idx] = f2bf(w[((size_t)sc * 256 + oc) * 2304 + c * 9 + z]);
}

// ---------------- conv1 weights -> tiled [cb2][r9][s40][kc4][row128][j8], *satt
__global__ void k_wperm1T(const float* __restrict__ w, const float* __restrict__ satt,
                          unsigned short* __restrict__ wp) {
  int idx = blockIdx.x * 256 + threadIdx.x;  // < 2*9*40*4096 = 2949120
  int j   = idx & 7;
  int row = (idx >> 3) & 127;
  int kc  = (idx >> 10) & 3;
  int rest = idx >> 12;          // (cb*9 + r)*40 + s
  int s = rest % 40; rest /= 40;
  int r = rest % 9;  int cb = rest / 9;
  int oc = cb * 128 + row;
  int ic = s * 32 + kc * 8 + j;  // < 1280
  wp[idx] = f2bf(w[(size_t)oc * 11520 + ic * 9 + r] * satt[ic]);
}

// ---------------- conv2 weights -> tiled [cb2][r9][s8][kc4][row128][j8] ----
__global__ void k_wperm2T(const float* __restrict__ w, unsigned short* __restrict__ wp) {
  int idx = blockIdx.x * 256 + threadIdx.x;  // < 2*9*8*4096 = 589824
  int j   = idx & 7;
  int row = (idx >> 3) & 127;
  int kc  = (idx >> 10) & 3;
  int rest = idx >> 12;          // (cb*9 + r)*8 + s
  int s = rest % 8; rest /= 8;
  int r = rest % 9; int cb = rest / 9;
  int oc = cb * 128 + row;
  int ic = s * 32 + kc * 8 + j;  // < 256
  wp[idx] = f2bf(w[(size_t)oc * 2304 + ic * 9 + r]);
}

// ---------------- tap table: per (z,n) box, 16 (byte-offset, weight) pairs -
// layout per box (128 B): int off[16]; float w[16].  weight folds
// sign * bilinear * 1/area; OOB taps -> (0, 0.0f).
// Degenerate (invisible) box: off[0] = -1 sentinel, rest unwritten.
__global__ void k_taps(const float* __restrict__ calib, int* __restrict__ taps,
                       int Hf, int Wf, float areaScale) {
  int idx = blockIdx.x * 256 + threadIdx.x;
  if (idx >= ZC * NBOX) return;
  int z = idx / NBOX, n = idx % NBOX;
  int d = n / 124, wj = n % 124;
  float P[12];
#pragma unroll
  for (int i = 0; i < 12; ++i) P[i] = calib[i];
  auto proj = [&](int k, int i, int j, float& nx, float& ny) {
    float X = 0.64f * (float)i;
    float Y = 39.68f - 0.64f * (float)j;
    float Z = 2.76f - 0.64f * (float)k;
    float hx = P[0] * X + P[1] * Y + P[2]  * Z + P[3];
    float hy = P[4] * X + P[5] * Y + P[6]  * Z + P[7];
    float hz = P[8] * X + P[9] * Y + P[10] * Z + P[11];
    float px = hx / hz, py = hy / hz;
    nx = 2.f * px / 1280.f - 1.f; nx = fminf(fmaxf(nx, -1.f), 1.f);
    ny = 2.f * py / 384.f  - 1.f; ny = fminf(fmaxf(ny, -1.f), 1.f);
  };
  float ax, ay, bx, by, cx, cy, dx, dy;
  proj(z,     d,     wj,     ax, ay);
  proj(z,     d + 1, wj,     bx, by);
  proj(z + 1, d + 1, wj + 1, cx, cy);
  proj(z + 1, d,     wj + 1, dx, dy);
  float x0 = fminf(ax, bx), y0 = fminf(ay, by);
  float x1 = fmaxf(cx, dx), y1 = fmaxf(cy, dy);
  float rawA = (x1 - x0) * (y1 - y0) * areaScale;
  if (!(rawA > 0.f)) { taps[(size_t)idx * 32] = -1; return; }
  float inv = 1.f / (rawA + 1e-6f);
  int   off[16];
  float w[16];
#pragma unroll
  for (int pt = 0; pt < 4; ++pt) {
    float gx = (pt == 0 || pt == 3) ? x0 : x1;
    float gy = (pt == 0 || pt == 2) ? y0 : y1;
    float sign = (pt < 2) ? 1.f : -1.f;
    float u = (gx + 1.f) * ((float)Wf * 0.5f) - 0.5f;
    float v = (gy + 1.f) * ((float)Hf * 0.5f) - 0.5f;
    float uf = floorf(u), vf = floorf(v);
    float wx = u - uf, wy = v - vf;
    int xi = (int)uf, yi = (int)vf;
#pragma unroll
    for (int t = 0; t < 4; ++t) {
      int xx = xi + (t & 1), yy = yi + (t >> 1);
      bool ok = ((unsigned)xx < (unsigned)Wf) && ((unsigned)yy < (unsigned)Hf);
      float wt = ((t & 1) ? wx : 1.f - wx) * ((t >> 1) ? wy : 1.f - wy);
      off[pt * 4 + t] = ok ? (yy * Wf + xx) * 1024 : 0;   // byte offset, 256ch*4B
      w[pt * 4 + t]   = ok ? sign * wt * inv : 0.f;
    }
  }
  int4v* ob = (int4v*)(taps + (size_t)idx * 32);
#pragma unroll
  for (int i = 0; i < 4; ++i)
    ob[i] = (int4v){off[4 * i], off[4 * i + 1], off[4 * i + 2], off[4 * i + 3]};
  float4v* wb = (float4v*)ob;
#pragma unroll
  for (int i = 0; i < 4; ++i)
    wb[4 + i] = (float4v){w[4 * i], w[4 * i + 1], w[4 * i + 2], w[4 * i + 3]};
}

// ---------------- merged feats transpose: [256][S] f32 -> II [S][256] ------
__global__ void k_transpose_all(const float* __restrict__ f0, const float* __restrict__ f1,
                                const float* __restrict__ f2, const float* __restrict__ f3,
                                const float* __restrict__ f4, float* __restrict__ II) {
  int b = blockIdx.x;
  int sc, cx;
  if (b < 480)      { sc = 0; cx = b; }
  else if (b < 600) { sc = 1; cx = b - 480; }
  else if (b < 630) { sc = 2; cx = b - 600; }
  else if (b < 638) { sc = 3; cx = b - 630; }
  else              { sc = 4; cx = b - 638; }
  const int Ss[5] = {30720, 7680, 1920, 480, 120};
  const size_t IIof[5] = {0, 7864320, 9830400, 10321920, 10444800};
  const float* srcs[5] = {f0, f1, f2, f3, f4};
  int S = Ss[sc];
  const float* src = srcs[sc];
  float* dst = II + IIof[sc];
  __shared__ float tile[64][65];
  int t = threadIdx.x;
  int wave = t >> 6, lane = t & 63;
  int s0 = cx * 64, c0 = blockIdx.y * 64;
#pragma unroll
  for (int i = 0; i < 16; ++i) {
    int c_l = wave * 16 + i;
    if (s0 + lane < S) tile[c_l][lane] = src[(size_t)(c0 + c_l) * S + s0 + lane];
  }
  __syncthreads();
#pragma unroll
  for (int i = 0; i < 16; ++i) {
    int s_l = wave * 16 + i;
    if (s0 + s_l < S) dst[(size_t)(s0 + s_l) * 256 + c0 + lane] = tile[lane][s_l];
  }
}

// ---------------- merged cumsum over w: grid 186 ---------------------------
__global__ void k_cumw_all(float* __restrict__ II) {
  int b = blockIdx.x;
  int sc, h;
  if (b < 96)       { sc = 0; h = b; }
  else if (b < 144) { sc = 1; h = b - 96; }
  else if (b < 168) { sc = 2; h = b - 144; }
  else if (b < 180) { sc = 3; h = b - 168; }
  else              { sc = 4; h = b - 180; }
  const int Wfs[5] = {320, 160, 80, 40, 20};
  const size_t IIof[5] = {0, 7864320, 9830400, 10321920, 10444800};
  int Wf = Wfs[sc];
  float* p = II + IIof[sc] + (size_t)h * Wf * 256 + threadIdx.x;
  float acc = 0.f;
#pragma unroll 4
  for (int w = 0; w < Wf; ++w) { acc += p[(size_t)w * 256]; p[(size_t)w * 256] = acc; }
}

// ---------------- merged cumsum over h: grid 620 ---------------------------
__global__ void k_cumh_all(float* __restrict__ II) {
  int b = blockIdx.x;
  int sc, w;
  if (b < 320)      { sc = 0; w = b; }
  else if (b < 480) { sc = 1; w = b - 320; }
  else if (b < 560) { sc = 2; w = b - 480; }
  else if (b < 600) { sc = 3; w = b - 560; }
  else              { sc = 4; w = b - 600; }
  const int Wfs[5] = {320, 160, 80, 40, 20};
  const int Hfs[5] = {96, 48, 24, 12, 6};
  const size_t IIof[5] = {0, 7864320, 9830400, 10321920, 10444800};
  int Hf = Hfs[sc];
  size_t stride = (size_t)Wfs[sc] * 256;
  float* p = II + IIof[sc] + (size_t)w * 256 + threadIdx.x;
  float acc = 0.f;
#pragma unroll 4
  for (int h = 0; h < Hf; ++h) { acc += p[h * stride]; p[h * stride] = acc; }
}

// ---------------- box sampler: wave = one n, 3 z per wave, table-driven ----
// XCD-locality swizzle: xcd = bx&7 gets contiguous 1/8 of the n-range.
__global__ void k_sample(const float* __restrict__ ii, const int* __restrict__ taps,
                         unsigned short* __restrict__ voxT) {
  int wave = threadIdx.x >> 6, lane = threadIdx.x & 63;
  int bx = blockIdx.x;
  int nb4 = (bx & 7) * 419 + (bx >> 3);
  if (nb4 >= NBOX / 4) return;
  int n = nb4 * 4 + wave;
  int zg = blockIdx.y * 3;
  const char* iib = (const char*)ii + (lane << 4);   // + c4*4 bytes
  int nb = n >> 7, row = n & 127;
  unsigned short* vb = voxT + (size_t)nb * NBSTRIDE + (size_t)row * 8
                     + (lane >> 3) * 4096 + ((lane >> 1) & 3) * 1024 + (lane & 1) * 4;
#pragma unroll
  for (int dz = 0; dz < 3; ++dz) {
    int z = zg + dz;
    const int* tbase = taps + (size_t)(z * NBOX + n) * 32;
    int flag = tbase[0];                 // wave-uniform broadcast
    ushort4v o;
    if (flag < 0) {                      // degenerate box: skip all 16 taps
      o[0] = 0; o[1] = 0; o[2] = 0; o[3] = 0;
    } else {
      const int4v* tb = (const int4v*)tbase;
      int4v o0 = tb[0], o1 = tb[1], o2 = tb[2], o3 = tb[3];
      const float4v* tw = (const float4v*)tb;
      float4v w0 = tw[4], w1 = tw[5], w2 = tw[6], w3 = tw[7];
      float4v a0 = {0.f, 0.f, 0.f, 0.f}, a1 = a0;
#define TAP(o, w, acc) { float4v t_ = *(const float4v*)(iib + (size_t)(unsigned)(o)); acc += t_ * (w); }
      TAP(o0.x, w0.x, a0) TAP(o0.y, w0.y, a1) TAP(o0.z, w0.z, a0) TAP(o0.w, w0.w, a1)
      TAP(o1.x, w1.x, a0) TAP(o1.y, w1.y, a1) TAP(o1.z, w1.z, a0) TAP(o1.w, w1.w, a1)
      TAP(o2.x, w2.x, a0) TAP(o2.y, w2.y, a1) TAP(o2.z, w2.z, a0) TAP(o2.w, w2.w, a1)
      TAP(o3.x, w3.x, a0) TAP(o3.y, w3.y, a1) TAP(o3.z, w3.z, a0) TAP(o3.w, w3.w, a1)
#undef TAP
      float4v acc = a0 + a1;
#pragma unroll
      for (int j = 0; j < 4; ++j) o[j] = f2bf(acc[j]);
    }
    *(ushort4v*)(vb + z * 32768) = o;
  }
}

// ---------------- OFT GEMM, split-K=4: raw f32 partials --------------------
__global__ __launch_bounds__(256) void k_gemmT(
    const unsigned short* __restrict__ AT, const unsigned short* __restrict__ BT,
    float* __restrict__ part) {
  __shared__ unsigned short lsA[4096];
  __shared__ unsigned short lsB[4096];
  int t = threadIdx.x;
  int lane = t & 63, wave = t >> 6;
  int l15 = lane & 15, quad = lane >> 4;
  int nb = blockIdx.x, cb = blockIdx.y, ks = blockIdx.z;
  int wrow = (wave >> 1) * 64, wcol = (wave & 1) * 64;

  const unsigned short* ga = AT + (size_t)nb * NBSTRIDE + (size_t)ks * 18 * TILEK + t * 8;
  const unsigned short* gb = BT + (size_t)cb * NBSTRIDE + (size_t)ks * 18 * TILEK + t * 8;
  unsigned short* ldA = lsA + t * 8;
  unsigned short* ldB = lsB + t * 8;

  float4v acc[4][4];
#pragma unroll
  for (int mi = 0; mi < 4; ++mi)
#pragma unroll
    for (int ni = 0; ni < 4; ++ni) acc[mi][ni] = (float4v){0.f, 0.f, 0.f, 0.f};

  for (int s = 0; s < 18; ++s) {
    async16(ga, ldA);
    async16(ga + 2048, ldA + 2048);
    async16(gb, ldB);
    async16(gb + 2048, ldB + 2048);
    ga += TILEK; gb += TILEK;
    __syncthreads();
    short8 af[4], bf[4];
    const short8* pA = (const short8*)lsA;
    const short8* pB = (const short8*)lsB;
#pragma unroll
    for (int mi = 0; mi < 4; ++mi) af[mi] = pA[quad * 128 + wrow + mi * 16 + l15];
#pragma unroll
    for (int ni = 0; ni < 4; ++ni) bf[ni] = pB[quad * 128 + wcol + ni * 16 + l15];
#pragma unroll
    for (int mi = 0; mi < 4; ++mi)
#pragma unroll
      for (int ni = 0; ni < 4; ++ni)
        acc[mi][ni] = __builtin_amdgcn_mfma_f32_16x16x32_bf16(af[mi], bf[ni], acc[mi][ni], 0, 0, 0);
    __syncthreads();
  }

#pragma unroll
  for (int mi = 0; mi < 4; ++mi) {
    int nb0 = nb * 128 + wrow + mi * 16 + quad * 4;
#pragma unroll
    for (int j = 0; j < 4; ++j) {
      int nn = nb0 + j;
      if (nn < NBOX) {
#pragma unroll
        for (int ni = 0; ni < 4; ++ni) {
          int oc = cb * 128 + wcol + ni * 16 + l15;
          part[((size_t)ks * NBOX + nn) * 256 + oc] = acc[mi][ni][j];
        }
      }
    }
  }
}

// reduce OFT partials -> XBUF [n][1280] @ choff (bias + relu, alpha=1)
__global__ void k_redoft(const float* __restrict__ part, const float* __restrict__ beta,
                         unsigned short* __restrict__ xbuf, int choff) {
  int n = blockIdx.x, oc = threadIdx.x;
  float v = part[(size_t)n * 256 + oc]
          + part[((size_t)NBOX + n) * 256 + oc]
          + part[((size_t)2 * NBOX + n) * 256 + oc]
          + part[((size_t)3 * NBOX + n) * 256 + oc];
  v += beta[oc];
  v = v > 0.f ? v : 0.f;
  xbuf[(size_t)n * 1280 + choff + oc] = f2bf(v);
}

// ---------------- conv GEMM, split by tap r: raw f32 partials --------------
template <int MODE>
__global__ __launch_bounds__(256) void k_gemmS(
    const unsigned short* __restrict__ A, const unsigned short* __restrict__ BT,
    float* __restrict__ part, const unsigned short* __restrict__ zpage) {
  constexpr int KIC   = (MODE == 1) ? 1280 : 256;
  constexpr int STEPS = KIC / 32;
  __shared__ unsigned short lsA[4096];
  __shared__ unsigned short lsB[4096];
  int t = threadIdx.x;
  int lane = t & 63, wave = t >> 6;
  int l15 = lane & 15, quad = lane >> 4;
  int n0 = blockIdx.x * 128, oc0 = blockIdx.y * 128;
  int r = blockIdx.z;
  int wrow = (wave >> 1) * 64, wcol = (wave & 1) * 64;
  int srow = t & 127, skc = t >> 7;

  int p = n0 + srow;
  int oy = p / 54, ox = p - oy * 54;
  int ky = r / 3, kx = r - ky * 3;
  bool valid; int sp;
  if (MODE == 1) {
    int ih = 2 * oy + ky - 1, iw = 2 * ox + kx - 1;
    valid = (p < NPIX) && ((unsigned)ih < 124u) && ((unsigned)iw < 108u);
    sp = iw * 124 + ih;
  } else {
    int ih = oy + ky - 1, iw = ox + kx - 1;
    valid = (p < NPIX) && ((unsigned)ih < 62u) && ((unsigned)iw < 54u);
    sp = ih * 54 + iw;
  }
  const unsigned short* ga = valid ? (A + (size_t)sp * KIC + skc * 8) : zpage;
  int astep = valid ? 32 : 0;
  const unsigned short* gb = BT + ((size_t)(blockIdx.y * 9 + r) * STEPS) * TILEK + t * 8;
  unsigned short* ldA = lsA + t * 8;
  unsigned short* ldB = lsB + t * 8;

  float4v acc[4][4];
#pragma unroll
  for (int mi = 0; mi < 4; ++mi)
#pragma unroll
    for (int ni = 0; ni < 4; ++ni) acc[mi][ni] = (float4v){0.f, 0.f, 0.f, 0.f};

  for (int s = 0; s < STEPS; ++s) {
    async16(ga, ldA);
    async16(ga + 16, ldA + 2048);
    async16(gb, ldB);
    async16(gb + 2048, ldB + 2048);
    ga += astep; gb += TILEK;
    __syncthreads();
    short8 af[4], bf[4];
    const short8* pA = (const short8*)lsA;
    const short8* pB = (const short8*)lsB;
#pragma unroll
    for (int mi = 0; mi < 4; ++mi) af[mi] = pA[quad * 128 + wrow + mi * 16 + l15];
#pragma unroll
    for (int ni = 0; ni < 4; ++ni) bf[ni] = pB[quad * 128 + wcol + ni * 16 + l15];
#pragma unroll
    for (int mi = 0; mi < 4; ++mi)
#pragma unroll
      for (int ni = 0; ni < 4; ++ni)
        acc[mi][ni] = __builtin_amdgcn_mfma_f32_16x16x32_bf16(af[mi], bf[ni], acc[mi][ni], 0, 0, 0);
    __syncthreads();
  }

#pragma unroll
  for (int mi = 0; mi < 4; ++mi) {
    int nb0 = n0 + wrow + mi * 16 + quad * 4;
#pragma unroll
    for (int j = 0; j < 4; ++j) {
      int nn = nb0 + j;
      if (nn < NPIX) {
#pragma unroll
        for (int ni = 0; ni < 4; ++ni) {
          int oc = oc0 + wcol + ni * 16 + l15;
          part[((size_t)r * NPIX + nn) * 256 + oc] = acc[mi][ni][j];
        }
      }
    }
  }
}

// reduce conv partials (9 taps) with alpha/beta + relu
template <bool F32OUT>
__global__ void k_redconv(const float* __restrict__ part, const float* __restrict__ alpha,
                          const float* __restrict__ beta, void* __restrict__ outv) {
  int p = blockIdx.x, oc = threadIdx.x;
  float v = 0.f;
#pragma unroll
  for (int r = 0; r < 9; ++r) v += part[((size_t)r * NPIX + p) * 256 + oc];
  v = v * alpha[oc] + beta[oc];
  v = v > 0.f ? v : 0.f;
  if (F32OUT) ((float*)outv)[(size_t)oc * NPIX + p] = v;
  else ((unsigned short*)outv)[(size_t)p * 256 + oc] = f2bf(v);
}

// ---------------- channel means over XBUF [n][1280] ------------------------
__global__ void k_means2(const unsigned short* __restrict__ x, float* __restrict__ means) {
  int tid = threadIdx.x;
  int r0 = blockIdx.x * 64;
  float part[5] = {0.f, 0.f, 0.f, 0.f, 0.f};
  for (int i = 0; i < 64; ++i) {
    int row = r0 + i;
    if (row < NBOX) {
      const unsigned short* rp = x + (size_t)row * 1280;
#pragma unroll
      for (int g = 0; g < 5; ++g) part[g] += bf2f(rp[g * 256 + tid]);
    }
  }
#pragma unroll
  for (int g = 0; g < 5; ++g) atomicAdd(&means[g * 256 + tid], part[g]);
}

__global__ void k_att(const float* __restrict__ means, const float* __restrict__ aw,
                      const float* __restrict__ ab, float* __restrict__ satt) {
  int sc = blockIdx.x, c = threadIdx.x;
  __shared__ float m[256];
  m[c] = means[sc * 256 + c] * (1.f / (float)NBOX);
  __syncthreads();
  float acc = ab[c];
  for (int j = 0; j < 256; ++j) acc += m[j] * aw[c * 256 + j];
  satt[sc * 256 + c] = 1.f / (1.f + expf(-acc));
}

extern "C" void kernel_launch(void* const* d_in, const int* in_sizes, int n_in,
                              void* d_out, int out_size, void* d_ws, size_t ws_size,
                              hipStream_t stream) {
  const float* feats[5];
  for (int i = 0; i < 5; ++i) feats[i] = (const float*)d_in[i];
  const float* calib   = (const float*)d_in[5];
  const float* oft_w   = (const float*)d_in[6];
  const float* oft_b   = (const float*)d_in[7];
  const float* att_w   = (const float*)d_in[8];
  const float* att_b   = (const float*)d_in[9];
  const float* conv1_w = (const float*)d_in[10];
  const float* bn1g = (const float*)d_in[11];
  const float* bn1b = (const float*)d_in[12];
  const float* bn1m = (const float*)d_in[13];
  const float* bn1v = (const float*)d_in[14];
  const float* conv2_w = (const float*)d_in[15];
  const float* bn2g = (const float*)d_in[16];
  const float* bn2b = (const float*)d_in[17];
  const float* bn2m = (const float*)d_in[18];
  const float* bn2v = (const float*)d_in[19];

  char* ws = (char*)d_ws;
  size_t off = 0;
  auto alloc = [&](size_t bytes) -> void* {
    void* p = ws + off; off += (bytes + 255) & ~(size_t)255; return p;
  };
  unsigned short* WPERMT = (unsigned short*)alloc((size_t)5 * 589824 * 2);
  unsigned short* WC1T   = (unsigned short*)alloc((size_t)2949120 * 2);
  unsigned short* WC2T   = (unsigned short*)alloc((size_t)589824 * 2);
  float*          II     = (float*)alloc((size_t)10475520 * 4);
  unsigned short* VOXT   = (unsigned short*)alloc((size_t)NBLK0 * NBSTRIDE * 2);
  unsigned short* XBUF   = (unsigned short*)alloc((size_t)NBOX * 1280 * 2);
  unsigned short* Y1     = (unsigned short*)alloc((size_t)NPIX * 256 * 2);
  float*          PART   = (float*)alloc((size_t)OFT_SPLIT * NBOX * 256 * 4); // 54.8 MB
  float*          MEANS  = (float*)alloc(1280 * 4);
  float*          SATT   = (float*)alloc(1280 * 4);
  float*          ALPHA  = (float*)alloc(7 * 256 * 4);
  float*          BETA   = (float*)alloc(7 * 256 * 4);
  unsigned short* ZPAGE  = (unsigned short*)alloc(256 * 2);
  // TAPS aliases PART: taps for scale s are consumed by k_sample(s) BEFORE
  // k_gemmT(s) writes PART; k_taps(s+1) runs after k_redoft(s) read PART.
  int* TAPS = (int*)PART;   // 9*13392*128 B = 15.4 MB <= 54.8 MB
  (void)ws_size; (void)in_sizes; (void)n_in; (void)out_size;

  static const int HFs[5] = {96, 48, 24, 12, 6};
  static const int WFs[5] = {320, 160, 80, 40, 20};
  static const size_t IIoff[5] = {0, 7864320, 9830400, 10321920, 10444800};

  k_alpha_beta<<<7, 256, 0, stream>>>(oft_b, bn1g, bn1b, bn1m, bn1v,
                                      bn2g, bn2b, bn2m, bn2v, ALPHA, BETA, MEANS, ZPAGE);
  k_wpermT<<<11520, 256, 0, stream>>>(oft_w, WPERMT);
  k_wperm2T<<<2304, 256, 0, stream>>>(conv2_w, WC2T);

  k_transpose_all<<<dim3(640, 4), 256, 0, stream>>>(feats[0], feats[1], feats[2],
                                                    feats[3], feats[4], II);
  k_cumw_all<<<186, 256, 0, stream>>>(II);
  k_cumh_all<<<620, 256, 0, stream>>>(II);

  for (int s = 0; s < 5; ++s) {
    k_taps<<<(ZC * NBOX + 255) / 256, 256, 0, stream>>>(
        calib, TAPS, HFs[s], WFs[s], (float)(HFs[s] * WFs[s]) * 0.25f);
    k_sample<<<dim3(3352, 3), 256, 0, stream>>>(II + IIoff[s], TAPS, VOXT);
    k_gemmT<<<dim3(NBLK0, 2, OFT_SPLIT), 256, 0, stream>>>(
        VOXT, WPERMT + (size_t)s * 589824, PART);
    k_redoft<<<NBOX, 256, 0, stream>>>(PART, BETA + s * 256, XBUF, s * 256);
  }
  k_means2<<<(NBOX + 63) / 64, 256, 0, stream>>>(XBUF, MEANS);
  k_att<<<5, 256, 0, stream>>>(MEANS, att_w, att_b, SATT);
  k_wperm1T<<<11520, 256, 0, stream>>>(conv1_w, SATT, WC1T);

  k_gemmS<1><<<dim3(NBLKC, 2, 9), 256, 0, stream>>>(XBUF, WC1T, PART, ZPAGE);
  k_redconv<false><<<NPIX, 256, 0, stream>>>(PART, ALPHA + 5 * 256, BETA + 5 * 256, Y1);

  k_gemmS<2><<<dim3(NBLKC, 2, 9), 256, 0, stream>>>(Y1, WC2T, PART, ZPAGE);
  k_redconv<true><<<NPIX, 256, 0, stream>>>(PART, ALPHA + 6 * 256, BETA + 6 * 256, d_out);
}

// Round 10
// 1001.536 us; speedup vs baseline: 1.0713x; 1.0692x over previous
//
#include <hip/hip_runtime.h>

typedef __attribute__((ext_vector_type(8))) short short8;
typedef __attribute__((ext_vector_type(4))) float float4v;
typedef __attribute__((ext_vector_type(4))) int int4v;
typedef __attribute__((ext_vector_type(4))) unsigned short ushort4v;

#define NBOX 13392   // 108*124 bev cells (n = d*124 + wj)
#define ZC 9
#define KOFT 2304    // 9*256, k = z*256+c
#define NPIX 3348    // 62*54
#define NBLK0 105    // ceil(13392/128)
#define NBLKC 27     // ceil(3348/128)
#define TILEK 4096   // shorts per 8KB step-tile [kc4][row128][8]
#define NBSTRIDE 294912  // 72 steps * 4096 shorts per row-block / col-block
#define OFT_SPLIT 4      // 18 steps per split chunk

__device__ __forceinline__ unsigned short f2bf(float f) {
  union { float f; unsigned int i; } v; v.f = f;
  unsigned int r = v.i + 0x7FFFu + ((v.i >> 16) & 1u);
  return (unsigned short)(r >> 16);
}
__device__ __forceinline__ float bf2f(unsigned short u) {
  union { unsigned int i; float f; } v; v.i = ((unsigned int)u) << 16; return v.f;
}
__device__ __forceinline__ float i2f(int i) {
  union { int i; float f; } v; v.i = i; return v.f;
}

// wave-uniform pointer: readfirstlane both halves so loads become s_load
__device__ __forceinline__ const int* uniform_ptr(const int* p) {
  unsigned lo = (unsigned)(uintptr_t)p;
  unsigned hi = (unsigned)((uintptr_t)p >> 32);
  lo = (unsigned)__builtin_amdgcn_readfirstlane((int)lo);
  hi = (unsigned)__builtin_amdgcn_readfirstlane((int)hi);
  return (const int*)(((uintptr_t)hi << 32) | (uintptr_t)lo);
}

// async 16B global->LDS (wave-uniform LDS base + lane*16)
__device__ __forceinline__ void async16(const unsigned short* g, unsigned short* l) {
  __builtin_amdgcn_global_load_lds(
      (const __attribute__((address_space(1))) unsigned int*)g,
      (__attribute__((address_space(3))) unsigned int*)l, 16, 0, 0);
}

// ---------------- alpha/beta epilogue constants + zero MEANS + zero page ---
__global__ void k_alpha_beta(const float* __restrict__ oft_b,
                             const float* __restrict__ g1, const float* __restrict__ b1,
                             const float* __restrict__ m1, const float* __restrict__ v1,
                             const float* __restrict__ g2, const float* __restrict__ b2,
                             const float* __restrict__ m2, const float* __restrict__ v2,
                             float* __restrict__ ALPHA, float* __restrict__ BETA,
                             float* __restrict__ MEANS, unsigned short* __restrict__ ZPAGE) {
  int g = blockIdx.x, c = threadIdx.x;
  float al, be;
  if (g < 5) { al = 1.f; be = oft_b[g * 256 + c]; MEANS[g * 256 + c] = 0.f; }
  else {
    const float* gg = (g == 5) ? g1 : g2;
    const float* bb = (g == 5) ? b1 : b2;
    const float* mm = (g == 5) ? m1 : m2;
    const float* vv = (g == 5) ? v1 : v2;
    al = gg[c] / sqrtf(vv[c] + 1e-5f);
    be = bb[c] - mm[c] * al;
  }
  ALPHA[g * 256 + c] = al; BETA[g * 256 + c] = be;
  if (g == 0) ZPAGE[c] = 0;
}

// ---------------- oft weights -> tiled B: [sc][cb2][s72][kc4][row128][j8] ---
__global__ void k_wpermT(const float* __restrict__ w, unsigned short* __restrict__ wp) {
  int idx = blockIdx.x * 256 + threadIdx.x;  // < 5*589824
  int sc = idx / 589824;
  int r  = idx % 589824;
  int j   = r & 7;
  int row = (r >> 3) & 127;
  int kc  = (r >> 10) & 3;
  int cs  = r >> 12;            // cb*72 + s
  int cb  = cs / 72, s = cs % 72;
  int oc = cb * 128 + row;
  int k  = s * 32 + kc * 8 + j; // k' = z*256 + c
  int z = k >> 8, c = k & 255;
  wp[idx] = f2bf(w[((size_t)sc * 256 + oc) * 2304 + c * 9 + z]);
}

// ---------------- conv1 weights -> tiled [cb2][r9][s40][kc4][row128][j8], *satt
__global__ void k_wperm1T(const float* __restrict__ w, const float* __restrict__ satt,
                          unsigned short* __restrict__ wp) {
  int idx = blockIdx.x * 256 + threadIdx.x;  // < 2*9*40*4096 = 2949120
  int j   = idx & 7;
  int row = (idx >> 3) & 127;
  int kc  = (idx >> 10) & 3;
  int rest = idx >> 12;          // (cb*9 + r)*40 + s
  int s = rest % 40; rest /= 40;
  int r = rest % 9;  int cb = rest / 9;
  int oc = cb * 128 + row;
  int ic = s * 32 + kc * 8 + j;  // < 1280
  wp[idx] = f2bf(w[(size_t)oc * 11520 + ic * 9 + r] * satt[ic]);
}

// ---------------- conv2 weights -> tiled [cb2][r9][s8][kc4][row128][j8] ----
__global__ void k_wperm2T(const float* __restrict__ w, unsigned short* __restrict__ wp) {
  int idx = blockIdx.x * 256 + threadIdx.x;  // < 2*9*8*4096 = 589824
  int j   = idx & 7;
  int row = (idx >> 3) & 127;
  int kc  = (idx >> 10) & 3;
  int rest = idx >> 12;          // (cb*9 + r)*8 + s
  int s = rest % 8; rest /= 8;
  int r = rest % 9; int cb = rest / 9;
  int oc = cb * 128 + row;
  int ic = s * 32 + kc * 8 + j;  // < 256
  wp[idx] = f2bf(w[(size_t)oc * 2304 + ic * 9 + r]);
}

// ---------------- tap table: per (z,n) box, 16 (byte-offset, weight) pairs -
// layout per box (128 B): int off[16]; float w[16].  weight folds
// sign * bilinear * 1/area; OOB taps -> (0, 0.0f).
// Degenerate (invisible) box: off[0] = -1 sentinel, rest unwritten.
__global__ void k_taps(const float* __restrict__ calib, int* __restrict__ taps,
                       int Hf, int Wf, float areaScale) {
  int idx = blockIdx.x * 256 + threadIdx.x;
  if (idx >= ZC * NBOX) return;
  int z = idx / NBOX, n = idx % NBOX;
  int d = n / 124, wj = n % 124;
  float P[12];
#pragma unroll
  for (int i = 0; i < 12; ++i) P[i] = calib[i];
  auto proj = [&](int k, int i, int j, float& nx, float& ny) {
    float X = 0.64f * (float)i;
    float Y = 39.68f - 0.64f * (float)j;
    float Z = 2.76f - 0.64f * (float)k;
    float hx = P[0] * X + P[1] * Y + P[2]  * Z + P[3];
    float hy = P[4] * X + P[5] * Y + P[6]  * Z + P[7];
    float hz = P[8] * X + P[9] * Y + P[10] * Z + P[11];
    float px = hx / hz, py = hy / hz;
    nx = 2.f * px / 1280.f - 1.f; nx = fminf(fmaxf(nx, -1.f), 1.f);
    ny = 2.f * py / 384.f  - 1.f; ny = fminf(fmaxf(ny, -1.f), 1.f);
  };
  float ax, ay, bx, by, cx, cy, dx, dy;
  proj(z,     d,     wj,     ax, ay);
  proj(z,     d + 1, wj,     bx, by);
  proj(z + 1, d + 1, wj + 1, cx, cy);
  proj(z + 1, d,     wj + 1, dx, dy);
  float x0 = fminf(ax, bx), y0 = fminf(ay, by);
  float x1 = fmaxf(cx, dx), y1 = fmaxf(cy, dy);
  float rawA = (x1 - x0) * (y1 - y0) * areaScale;
  if (!(rawA > 0.f)) { taps[(size_t)idx * 32] = -1; return; }
  float inv = 1.f / (rawA + 1e-6f);
  int   off[16];
  float w[16];
#pragma unroll
  for (int pt = 0; pt < 4; ++pt) {
    float gx = (pt == 0 || pt == 3) ? x0 : x1;
    float gy = (pt == 0 || pt == 2) ? y0 : y1;
    float sign = (pt < 2) ? 1.f : -1.f;
    float u = (gx + 1.f) * ((float)Wf * 0.5f) - 0.5f;
    float v = (gy + 1.f) * ((float)Hf * 0.5f) - 0.5f;
    float uf = floorf(u), vf = floorf(v);
    float wx = u - uf, wy = v - vf;
    int xi = (int)uf, yi = (int)vf;
#pragma unroll
    for (int t = 0; t < 4; ++t) {
      int xx = xi + (t & 1), yy = yi + (t >> 1);
      bool ok = ((unsigned)xx < (unsigned)Wf) && ((unsigned)yy < (unsigned)Hf);
      float wt = ((t & 1) ? wx : 1.f - wx) * ((t >> 1) ? wy : 1.f - wy);
      off[pt * 4 + t] = ok ? (yy * Wf + xx) * 1024 : 0;   // byte offset, 256ch*4B
      w[pt * 4 + t]   = ok ? sign * wt * inv : 0.f;
    }
  }
  int4v* ob = (int4v*)(taps + (size_t)idx * 32);
#pragma unroll
  for (int i = 0; i < 4; ++i)
    ob[i] = (int4v){off[4 * i], off[4 * i + 1], off[4 * i + 2], off[4 * i + 3]};
  float4v* wb = (float4v*)ob;
#pragma unroll
  for (int i = 0; i < 4; ++i)
    wb[4 + i] = (float4v){w[4 * i], w[4 * i + 1], w[4 * i + 2], w[4 * i + 3]};
}

// ---------------- merged feats transpose: [256][S] f32 -> II [S][256] ------
__global__ void k_transpose_all(const float* __restrict__ f0, const float* __restrict__ f1,
                                const float* __restrict__ f2, const float* __restrict__ f3,
                                const float* __restrict__ f4, float* __restrict__ II) {
  int b = blockIdx.x;
  int sc, cx;
  if (b < 480)      { sc = 0; cx = b; }
  else if (b < 600) { sc = 1; cx = b - 480; }
  else if (b < 630) { sc = 2; cx = b - 600; }
  else if (b < 638) { sc = 3; cx = b - 630; }
  else              { sc = 4; cx = b - 638; }
  const int Ss[5] = {30720, 7680, 1920, 480, 120};
  const size_t IIof[5] = {0, 7864320, 9830400, 10321920, 10444800};
  const float* srcs[5] = {f0, f1, f2, f3, f4};
  int S = Ss[sc];
  const float* src = srcs[sc];
  float* dst = II + IIof[sc];
  __shared__ float tile[64][65];
  int t = threadIdx.x;
  int wave = t >> 6, lane = t & 63;
  int s0 = cx * 64, c0 = blockIdx.y * 64;
#pragma unroll
  for (int i = 0; i < 16; ++i) {
    int c_l = wave * 16 + i;
    if (s0 + lane < S) tile[c_l][lane] = src[(size_t)(c0 + c_l) * S + s0 + lane];
  }
  __syncthreads();
#pragma unroll
  for (int i = 0; i < 16; ++i) {
    int s_l = wave * 16 + i;
    if (s0 + s_l < S) dst[(size_t)(s0 + s_l) * 256 + c0 + lane] = tile[lane][s_l];
  }
}

// ---------------- merged cumsum over w: grid 186 ---------------------------
__global__ void k_cumw_all(float* __restrict__ II) {
  int b = blockIdx.x;
  int sc, h;
  if (b < 96)       { sc = 0; h = b; }
  else if (b < 144) { sc = 1; h = b - 96; }
  else if (b < 168) { sc = 2; h = b - 144; }
  else if (b < 180) { sc = 3; h = b - 168; }
  else              { sc = 4; h = b - 180; }
  const int Wfs[5] = {320, 160, 80, 40, 20};
  const size_t IIof[5] = {0, 7864320, 9830400, 10321920, 10444800};
  int Wf = Wfs[sc];
  float* p = II + IIof[sc] + (size_t)h * Wf * 256 + threadIdx.x;
  float acc = 0.f;
#pragma unroll 4
  for (int w = 0; w < Wf; ++w) { acc += p[(size_t)w * 256]; p[(size_t)w * 256] = acc; }
}

// ---------------- merged cumsum over h: grid 620 ---------------------------
__global__ void k_cumh_all(float* __restrict__ II) {
  int b = blockIdx.x;
  int sc, w;
  if (b < 320)      { sc = 0; w = b; }
  else if (b < 480) { sc = 1; w = b - 320; }
  else if (b < 560) { sc = 2; w = b - 480; }
  else if (b < 600) { sc = 3; w = b - 560; }
  else              { sc = 4; w = b - 600; }
  const int Wfs[5] = {320, 160, 80, 40, 20};
  const int Hfs[5] = {96, 48, 24, 12, 6};
  const size_t IIof[5] = {0, 7864320, 9830400, 10321920, 10444800};
  int Hf = Hfs[sc];
  size_t stride = (size_t)Wfs[sc] * 256;
  float* p = II + IIof[sc] + (size_t)w * 256 + threadIdx.x;
  float acc = 0.f;
#pragma unroll 4
  for (int h = 0; h < Hf; ++h) { acc += p[h * stride]; p[h * stride] = acc; }
}

// ---------------- box sampler: wave = one n, 3 z per wave ------------------
// Tap table read via SCALAR path (s_load) — wave-uniform pointer; only the
// 16 tap loads + 1 store use the vector memory pipe.
__global__ void k_sample(const float* __restrict__ ii, const int* __restrict__ taps,
                         unsigned short* __restrict__ voxT) {
  int wave = threadIdx.x >> 6, lane = threadIdx.x & 63;
  int n = blockIdx.x * 4 + wave;
  int zg = blockIdx.y * 3;
  const char* iib = (const char*)ii + (lane << 4);   // + c4*4 bytes
  int nb = n >> 7, row = n & 127;
  unsigned short* vb = voxT + (size_t)nb * NBSTRIDE + (size_t)row * 8
                     + (lane >> 3) * 4096 + ((lane >> 1) & 3) * 1024 + (lane & 1) * 4;
#pragma unroll
  for (int dz = 0; dz < 3; ++dz) {
    int z = zg + dz;
    const int* tb = uniform_ptr(taps + (size_t)(z * NBOX + n) * 32);
    int o_[16];
#pragma unroll
    for (int i = 0; i < 16; ++i) o_[i] = tb[i];     // s_load (SGPRs)
    ushort4v o;
    if (o_[0] < 0) {                      // degenerate box: no vector loads
      o[0] = 0; o[1] = 0; o[2] = 0; o[3] = 0;
    } else {
      float w_[16];
#pragma unroll
      for (int i = 0; i < 16; ++i) w_[i] = i2f(tb[16 + i]);  // s_load (SGPRs)
      float4v a0 = {0.f, 0.f, 0.f, 0.f}, a1 = a0;
#define TAP(i, acc) { float4v t_ = *(const float4v*)(iib + (size_t)(unsigned)o_[i]); acc += t_ * w_[i]; }
      TAP(0, a0) TAP(1, a1) TAP(2, a0) TAP(3, a1)
      TAP(4, a0) TAP(5, a1) TAP(6, a0) TAP(7, a1)
      TAP(8, a0) TAP(9, a1) TAP(10, a0) TAP(11, a1)
      TAP(12, a0) TAP(13, a1) TAP(14, a0) TAP(15, a1)
#undef TAP
      float4v acc = a0 + a1;
#pragma unroll
      for (int j = 0; j < 4; ++j) o[j] = f2bf(acc[j]);
    }
    *(ushort4v*)(vb + z * 32768) = o;
  }
}

// ---------------- OFT GEMM, split-K=4: raw f32 partials --------------------
__global__ __launch_bounds__(256) void k_gemmT(
    const unsigned short* __restrict__ AT, const unsigned short* __restrict__ BT,
    float* __restrict__ part) {
  __shared__ unsigned short lsA[4096];
  __shared__ unsigned short lsB[4096];
  int t = threadIdx.x;
  int lane = t & 63, wave = t >> 6;
  int l15 = lane & 15, quad = lane >> 4;
  int nb = blockIdx.x, cb = blockIdx.y, ks = blockIdx.z;
  int wrow = (wave >> 1) * 64, wcol = (wave & 1) * 64;

  const unsigned short* ga = AT + (size_t)nb * NBSTRIDE + (size_t)ks * 18 * TILEK + t * 8;
  const unsigned short* gb = BT + (size_t)cb * NBSTRIDE + (size_t)ks * 18 * TILEK + t * 8;
  unsigned short* ldA = lsA + t * 8;
  unsigned short* ldB = lsB + t * 8;

  float4v acc[4][4];
#pragma unroll
  for (int mi = 0; mi < 4; ++mi)
#pragma unroll
    for (int ni = 0; ni < 4; ++ni) acc[mi][ni] = (float4v){0.f, 0.f, 0.f, 0.f};

  for (int s = 0; s < 18; ++s) {
    async16(ga, ldA);
    async16(ga + 2048, ldA + 2048);
    async16(gb, ldB);
    async16(gb + 2048, ldB + 2048);
    ga += TILEK; gb += TILEK;
    __syncthreads();
    short8 af[4], bf[4];
    const short8* pA = (const short8*)lsA;
    const short8* pB = (const short8*)lsB;
#pragma unroll
    for (int mi = 0; mi < 4; ++mi) af[mi] = pA[quad * 128 + wrow + mi * 16 + l15];
#pragma unroll
    for (int ni = 0; ni < 4; ++ni) bf[ni] = pB[quad * 128 + wcol + ni * 16 + l15];
#pragma unroll
    for (int mi = 0; mi < 4; ++mi)
#pragma unroll
      for (int ni = 0; ni < 4; ++ni)
        acc[mi][ni] = __builtin_amdgcn_mfma_f32_16x16x32_bf16(af[mi], bf[ni], acc[mi][ni], 0, 0, 0);
    __syncthreads();
  }

#pragma unroll
  for (int mi = 0; mi < 4; ++mi) {
    int nb0 = nb * 128 + wrow + mi * 16 + quad * 4;
#pragma unroll
    for (int j = 0; j < 4; ++j) {
      int nn = nb0 + j;
      if (nn < NBOX) {
#pragma unroll
        for (int ni = 0; ni < 4; ++ni) {
          int oc = cb * 128 + wcol + ni * 16 + l15;
          part[((size_t)ks * NBOX + nn) * 256 + oc] = acc[mi][ni][j];
        }
      }
    }
  }
}

// reduce OFT partials -> XBUF [n][1280] @ choff (bias + relu, alpha=1)
__global__ void k_redoft(const float* __restrict__ part, const float* __restrict__ beta,
                         unsigned short* __restrict__ xbuf, int choff) {
  int n = blockIdx.x, oc = threadIdx.x;
  float v = part[(size_t)n * 256 + oc]
          + part[((size_t)NBOX + n) * 256 + oc]
          + part[((size_t)2 * NBOX + n) * 256 + oc]
          + part[((size_t)3 * NBOX + n) * 256 + oc];
  v += beta[oc];
  v = v > 0.f ? v : 0.f;
  xbuf[(size_t)n * 1280 + choff + oc] = f2bf(v);
}

// ---------------- conv GEMM, split by tap r: raw f32 partials --------------
template <int MODE>
__global__ __launch_bounds__(256) void k_gemmS(
    const unsigned short* __restrict__ A, const unsigned short* __restrict__ BT,
    float* __restrict__ part, const unsigned short* __restrict__ zpage) {
  constexpr int KIC   = (MODE == 1) ? 1280 : 256;
  constexpr int STEPS = KIC / 32;
  __shared__ unsigned short lsA[4096];
  __shared__ unsigned short lsB[4096];
  int t = threadIdx.x;
  int lane = t & 63, wave = t >> 6;
  int l15 = lane & 15, quad = lane >> 4;
  int n0 = blockIdx.x * 128, oc0 = blockIdx.y * 128;
  int r = blockIdx.z;
  int wrow = (wave >> 1) * 64, wcol = (wave & 1) * 64;
  int srow = t & 127, skc = t >> 7;

  int p = n0 + srow;
  int oy = p / 54, ox = p - oy * 54;
  int ky = r / 3, kx = r - ky * 3;
  bool valid; int sp;
  if (MODE == 1) {
    int ih = 2 * oy + ky - 1, iw = 2 * ox + kx - 1;
    valid = (p < NPIX) && ((unsigned)ih < 124u) && ((unsigned)iw < 108u);
    sp = iw * 124 + ih;
  } else {
    int ih = oy + ky - 1, iw = ox + kx - 1;
    valid = (p < NPIX) && ((unsigned)ih < 62u) && ((unsigned)iw < 54u);
    sp = ih * 54 + iw;
  }
  const unsigned short* ga = valid ? (A + (size_t)sp * KIC + skc * 8) : zpage;
  int astep = valid ? 32 : 0;
  const unsigned short* gb = BT + ((size_t)(blockIdx.y * 9 + r) * STEPS) * TILEK + t * 8;
  unsigned short* ldA = lsA + t * 8;
  unsigned short* ldB = lsB + t * 8;

  float4v acc[4][4];
#pragma unroll
  for (int mi = 0; mi < 4; ++mi)
#pragma unroll
    for (int ni = 0; ni < 4; ++ni) acc[mi][ni] = (float4v){0.f, 0.f, 0.f, 0.f};

  for (int s = 0; s < STEPS; ++s) {
    async16(ga, ldA);
    async16(ga + 16, ldA + 2048);
    async16(gb, ldB);
    async16(gb + 2048, ldB + 2048);
    ga += astep; gb += TILEK;
    __syncthreads();
    short8 af[4], bf[4];
    const short8* pA = (const short8*)lsA;
    const short8* pB = (const short8*)lsB;
#pragma unroll
    for (int mi = 0; mi < 4; ++mi) af[mi] = pA[quad * 128 + wrow + mi * 16 + l15];
#pragma unroll
    for (int ni = 0; ni < 4; ++ni) bf[ni] = pB[quad * 128 + wcol + ni * 16 + l15];
#pragma unroll
    for (int mi = 0; mi < 4; ++mi)
#pragma unroll
      for (int ni = 0; ni < 4; ++ni)
        acc[mi][ni] = __builtin_amdgcn_mfma_f32_16x16x32_bf16(af[mi], bf[ni], acc[mi][ni], 0, 0, 0);
    __syncthreads();
  }

#pragma unroll
  for (int mi = 0; mi < 4; ++mi) {
    int nb0 = n0 + wrow + mi * 16 + quad * 4;
#pragma unroll
    for (int j = 0; j < 4; ++j) {
      int nn = nb0 + j;
      if (nn < NPIX) {
#pragma unroll
        for (int ni = 0; ni < 4; ++ni) {
          int oc = oc0 + wcol + ni * 16 + l15;
          part[((size_t)r * NPIX + nn) * 256 + oc] = acc[mi][ni][j];
        }
      }
    }
  }
}

// reduce conv partials (9 taps) with alpha/beta + relu
template <bool F32OUT>
__global__ void k_redconv(const float* __restrict__ part, const float* __restrict__ alpha,
                          const float* __restrict__ beta, void* __restrict__ outv) {
  int p = blockIdx.x, oc = threadIdx.x;
  float v = 0.f;
#pragma unroll
  for (int r = 0; r < 9; ++r) v += part[((size_t)r * NPIX + p) * 256 + oc];
  v = v * alpha[oc] + beta[oc];
  v = v > 0.f ? v : 0.f;
  if (F32OUT) ((float*)outv)[(size_t)oc * NPIX + p] = v;
  else ((unsigned short*)outv)[(size_t)p * 256 + oc] = f2bf(v);
}

// ---------------- channel means over XBUF [n][1280] ------------------------
__global__ void k_means2(const unsigned short* __restrict__ x, float* __restrict__ means) {
  int tid = threadIdx.x;
  int r0 = blockIdx.x * 64;
  float part[5] = {0.f, 0.f, 0.f, 0.f, 0.f};
  for (int i = 0; i < 64; ++i) {
    int row = r0 + i;
    if (row < NBOX) {
      const unsigned short* rp = x + (size_t)row * 1280;
#pragma unroll
      for (int g = 0; g < 5; ++g) part[g] += bf2f(rp[g * 256 + tid]);
    }
  }
#pragma unroll
  for (int g = 0; g < 5; ++g) atomicAdd(&means[g * 256 + tid], part[g]);
}

__global__ void k_att(const float* __restrict__ means, const float* __restrict__ aw,
                      const float* __restrict__ ab, float* __restrict__ satt) {
  int sc = blockIdx.x, c = threadIdx.x;
  __shared__ float m[256];
  m[c] = means[sc * 256 + c] * (1.f / (float)NBOX);
  __syncthreads();
  float acc = ab[c];
  for (int j = 0; j < 256; ++j) acc += m[j] * aw[c * 256 + j];
  satt[sc * 256 + c] = 1.f / (1.f + expf(-acc));
}

extern "C" void kernel_launch(void* const* d_in, const int* in_sizes, int n_in,
                              void* d_out, int out_size, void* d_ws, size_t ws_size,
                              hipStream_t stream) {
  const float* feats[5];
  for (int i = 0; i < 5; ++i) feats[i] = (const float*)d_in[i];
  const float* calib   = (const float*)d_in[5];
  const float* oft_w   = (const float*)d_in[6];
  const float* oft_b   = (const float*)d_in[7];
  const float* att_w   = (const float*)d_in[8];
  const float* att_b   = (const float*)d_in[9];
  const float* conv1_w = (const float*)d_in[10];
  const float* bn1g = (const float*)d_in[11];
  const float* bn1b = (const float*)d_in[12];
  const float* bn1m = (const float*)d_in[13];
  const float* bn1v = (const float*)d_in[14];
  const float* conv2_w = (const float*)d_in[15];
  const float* bn2g = (const float*)d_in[16];
  const float* bn2b = (const float*)d_in[17];
  const float* bn2m = (const float*)d_in[18];
  const float* bn2v = (const float*)d_in[19];

  char* ws = (char*)d_ws;
  size_t off = 0;
  auto alloc = [&](size_t bytes) -> void* {
    void* p = ws + off; off += (bytes + 255) & ~(size_t)255; return p;
  };
  unsigned short* WPERMT = (unsigned short*)alloc((size_t)5 * 589824 * 2);
  unsigned short* WC1T   = (unsigned short*)alloc((size_t)2949120 * 2);
  unsigned short* WC2T   = (unsigned short*)alloc((size_t)589824 * 2);
  float*          II     = (float*)alloc((size_t)10475520 * 4);
  unsigned short* VOXT   = (unsigned short*)alloc((size_t)NBLK0 * NBSTRIDE * 2);
  unsigned short* XBUF   = (unsigned short*)alloc((size_t)NBOX * 1280 * 2);
  unsigned short* Y1     = (unsigned short*)alloc((size_t)NPIX * 256 * 2);
  float*          PART   = (float*)alloc((size_t)OFT_SPLIT * NBOX * 256 * 4); // 54.8 MB
  float*          MEANS  = (float*)alloc(1280 * 4);
  float*          SATT   = (float*)alloc(1280 * 4);
  float*          ALPHA  = (float*)alloc(7 * 256 * 4);
  float*          BETA   = (float*)alloc(7 * 256 * 4);
  unsigned short* ZPAGE  = (unsigned short*)alloc(256 * 2);
  // TAPS aliases PART: taps for scale s are consumed by k_sample(s) BEFORE
  // k_gemmT(s) writes PART; k_taps(s+1) runs after k_redoft(s) read PART.
  int* TAPS = (int*)PART;   // 9*13392*128 B = 15.4 MB <= 54.8 MB
  (void)ws_size; (void)in_sizes; (void)n_in; (void)out_size;

  static const int HFs[5] = {96, 48, 24, 12, 6};
  static const int WFs[5] = {320, 160, 80, 40, 20};
  static const size_t IIoff[5] = {0, 7864320, 9830400, 10321920, 10444800};

  k_alpha_beta<<<7, 256, 0, stream>>>(oft_b, bn1g, bn1b, bn1m, bn1v,
                                      bn2g, bn2b, bn2m, bn2v, ALPHA, BETA, MEANS, ZPAGE);
  k_wpermT<<<11520, 256, 0, stream>>>(oft_w, WPERMT);
  k_wperm2T<<<2304, 256, 0, stream>>>(conv2_w, WC2T);

  k_transpose_all<<<dim3(640, 4), 256, 0, stream>>>(feats[0], feats[1], feats[2],
                                                    feats[3], feats[4], II);
  k_cumw_all<<<186, 256, 0, stream>>>(II);
  k_cumh_all<<<620, 256, 0, stream>>>(II);

  for (int s = 0; s < 5; ++s) {
    k_taps<<<(ZC * NBOX + 255) / 256, 256, 0, stream>>>(
        calib, TAPS, HFs[s], WFs[s], (float)(HFs[s] * WFs[s]) * 0.25f);
    k_sample<<<dim3(NBOX / 4, 3), 256, 0, stream>>>(II + IIoff[s], TAPS, VOXT);
    k_gemmT<<<dim3(NBLK0, 2, OFT_SPLIT), 256, 0, stream>>>(
        VOXT, WPERMT + (size_t)s * 589824, PART);
    k_redoft<<<NBOX, 256, 0, stream>>>(PART, BETA + s * 256, XBUF, s * 256);
  }
  k_means2<<<(NBOX + 63) / 64, 256, 0, stream>>>(XBUF, MEANS);
  k_att<<<5, 256, 0, stream>>>(MEANS, att_w, att_b, SATT);
  k_wperm1T<<<11520, 256, 0, stream>>>(conv1_w, SATT, WC1T);

  k_gemmS<1><<<dim3(NBLKC, 2, 9), 256, 0, stream>>>(XBUF, WC1T, PART, ZPAGE);
  k_redconv<false><<<NPIX, 256, 0, stream>>>(PART, ALPHA + 5 * 256, BETA + 5 * 256, Y1);

  k_gemmS<2><<<dim3(NBLKC, 2, 9), 256, 0, stream>>>(Y1, WC2T, PART, ZPAGE);
  k_redconv<true><<<NPIX, 256, 0, stream>>>(PART, ALPHA + 6 * 256, BETA + 6 * 256, d_out);
}